// Round 1
// baseline (30256.647 us; speedup 1.0000x reference)
//
#include <hip/hip_runtime.h>
#include <hip/hip_bf16.h>

#define NB 16
#define NBLK 128
#define TT 512
#define DD 20

using bf16x8 = __attribute__((ext_vector_type(8))) short;
using f32x4  = __attribute__((ext_vector_type(4))) float;

// workspace byte offsets
#define OFF_WIH0  0          // 1024x20  -> 64 tiles x 1 kt  : 32768 bf16 = 65536 B
#define OFF_WHH0  65536      // 1024x256 -> 64 x 8           : 262144 bf16 = 524288 B
#define OFF_WIH1  589824
#define OFF_WHH1  1114112
#define OFF_WPROJ 1638400    // 20x256 -> 2 x 8              : 8192 bf16 = 16384 B
#define OFF_B0    1654784    // 1024 f32
#define OFF_B1    1658880    // 1024 f32

__device__ __forceinline__ float sigf(float x) { return 1.0f / (1.0f + __expf(-x)); }
__device__ __forceinline__ float tanhfast(float x) { return 1.0f - 2.0f / (__expf(2.0f * x) + 1.0f); }

// ---- prep: fp32 weights -> bf16, swizzled into MFMA B-fragment order ----
// B-frag for mfma_f32_16x16x32_bf16: lane L holds B[k = kt*32 + (L>>4)*8 + j][n = nt*16 + (L&15)], j=0..7
// flat element e = ((nt*nKt + kt)*64 + lane)*8 + j
__global__ void prep_kernel(const float* __restrict__ wih0, const float* __restrict__ whh0,
                            const float* __restrict__ wih1, const float* __restrict__ whh1,
                            const float* __restrict__ wproj,
                            const float* __restrict__ bih0, const float* __restrict__ bhh0,
                            const float* __restrict__ bih1, const float* __restrict__ bhh1,
                            char* __restrict__ ws) {
    int idx = blockIdx.x * 256 + threadIdx.x;
    const float* src;
    __hip_bfloat16* dst;
    int e, N, K, nKt;
    if (idx < 32768)       { e = idx;          src = wih0;  N = 1024; K = 20;  nKt = 1; dst = (__hip_bfloat16*)(ws + OFF_WIH0); }
    else if (idx < 294912) { e = idx - 32768;  src = whh0;  N = 1024; K = 256; nKt = 8; dst = (__hip_bfloat16*)(ws + OFF_WHH0); }
    else if (idx < 557056) { e = idx - 294912; src = wih1;  N = 1024; K = 256; nKt = 8; dst = (__hip_bfloat16*)(ws + OFF_WIH1); }
    else if (idx < 819200) { e = idx - 557056; src = whh1;  N = 1024; K = 256; nKt = 8; dst = (__hip_bfloat16*)(ws + OFF_WHH1); }
    else if (idx < 827392) { e = idx - 819200; src = wproj; N = 20;   K = 256; nKt = 8; dst = (__hip_bfloat16*)(ws + OFF_WPROJ); }
    else if (idx < 828416) { int j = idx - 827392; ((float*)(ws + OFF_B0))[j] = bih0[j] + bhh0[j]; return; }
    else if (idx < 829440) { int j = idx - 828416; ((float*)(ws + OFF_B1))[j] = bih1[j] + bhh1[j]; return; }
    else return;
    int j    = e & 7;
    int lane = (e >> 3) & 63;
    int tile = e >> 9;
    int kt = tile % nKt;
    int nt = tile / nKt;
    int n = nt * 16 + (lane & 15);
    int k = kt * 32 + ((lane >> 4) << 3) + j;
    float v = (n < N && k < K) ? src[n * K + k] : 0.0f;
    dst[e] = __float2bfloat16(v);
}

// ---- persistent decoder: 128 blocks x 512 threads, 16 batch rows/block, 512 steps ----
__global__ __launch_bounds__(512, 2) void decoder_kernel(
    const float* __restrict__ z, const float* __restrict__ w_lh, const float* __restrict__ b_lh,
    const float* __restrict__ w_lc, const float* __restrict__ b_lc,
    const float* __restrict__ b_proj, const char* __restrict__ ws,
    float* __restrict__ out) {

    __shared__ __align__(16) __hip_bfloat16 h0b[2][16][264]; // +8 pad, rows 528 B (16B-aligned)
    __shared__ __align__(16) __hip_bfloat16 h1b[2][16][264];
    __shared__ __align__(16) __hip_bfloat16 xb[16][32];      // K padded 20->32 with zeros
    __shared__ float cinit[2][16][256];
    __shared__ float zb[16][32];

    const int tid = threadIdx.x;
    const int blk = blockIdx.x;
    const int b0  = blk * NB;

    // stage z, zero x0
    {
        int i = tid; // 512 threads cover 16*32
        zb[i >> 5][i & 31] = z[(b0 + (i >> 5)) * 32 + (i & 31)];
        xb[i >> 5][i & 31] = __float2bfloat16(0.0f);
    }
    __syncthreads();

    // h/c init: h_init = z @ w_lh.T + b_lh ; c_init = z @ w_lc.T + b_lc (fp32 VALU, K=32)
    for (int ii = 0; ii < 16; ii++) {
        int pi = ii * 512 + tid;
        int b = pi >> 9, col = pi & 511;
        float dh = b_lh[col], dc = b_lc[col];
        #pragma unroll 8
        for (int k = 0; k < 32; k++) {
            float zv = zb[b][k];
            dh += zv * w_lh[col * 32 + k];
            dc += zv * w_lc[col * 32 + k];
        }
        if (col < 256) { h0b[0][b][col]       = __float2bfloat16(dh); cinit[0][b][col]       = dc; }
        else           { h1b[0][b][col - 256] = __float2bfloat16(dh); cinit[1][b][col - 256] = dc; }
    }
    __syncthreads();

    const int wv = tid >> 6, ln = tid & 63;
    const int l15 = ln & 15, lq = ln >> 4;

    // c-state: lane-local per C/D layout (b = lq*4+r, u = wv*32 + h*16 + l15)
    float c0r[2][4], c1r[2][4];
    #pragma unroll
    for (int h = 0; h < 2; h++)
        #pragma unroll
        for (int r = 0; r < 4; r++) {
            int u = wv * 32 + h * 16 + l15, b = lq * 4 + r;
            c0r[h][r] = cinit[0][b][u];
            c1r[h][r] = cinit[1][b][u];
        }

    const float* bias0 = (const float*)(ws + OFF_B0);
    const float* bias1 = (const float*)(ws + OFF_B1);
    float bs0[8], bs1[8];
    #pragma unroll
    for (int q = 0; q < 8; q++) {
        int col = (q >> 1) * 256 + wv * 32 + (q & 1) * 16 + l15;
        bs0[q] = bias0[col];
        bs1[q] = bias1[col];
    }
    float bpj0 = b_proj[l15];
    float bpj1 = (l15 < 4) ? b_proj[16 + l15] : 0.0f;

    // wave tile map: q = g*2+h -> global n_tile = g*16 + wv*2 + h (col base 256g + 32wv + 16h)
    int bo8[8], bo1[8];
    #pragma unroll
    for (int q = 0; q < 8; q++) {
        int tbq = (q >> 1) * 16 + wv * 2 + (q & 1);
        bo8[q] = tbq * 8192 + ln * 16; // nKt=8 matrices: + kt*1024
        bo1[q] = tbq * 1024 + ln * 16; // nKt=1 matrix
    }

    const char* W0x = ws + OFF_WIH0;
    const char* W0h = ws + OFF_WHH0;
    const char* W1x = ws + OFF_WIH1;
    const char* W1h = ws + OFF_WHH1;
    const char* Wp  = ws + OFF_WPROJ;

    const char* hA = (const char*)&h0b[0][0][0];
    const char* hB = (const char*)&h1b[0][0][0];
    const int aoff = l15 * 528 + lq * 16; // A-frag: lane reads h[m=l15][kt*32 + lq*8 .. +8]
    const char* xA = (const char*)&xb[0][0] + l15 * 64 + lq * 16;

    float* outp = out + (size_t)b0 * TT * DD;

    #pragma unroll 1
    for (int t = 0; t < TT; t++) {
        const int p = t & 1;
        // ---------- phase A: gates0 = x @ w_ih0.T + h0 @ w_hh0.T + bias0 ----------
        f32x4 acc[8];
        #pragma unroll
        for (int q = 0; q < 8; q++) { f32x4 v = {bs0[q], bs0[q], bs0[q], bs0[q]}; acc[q] = v; }

        bf16x8 ax = *(const bf16x8*)xA;
        #pragma unroll
        for (int q = 0; q < 8; q++) {
            bf16x8 bx = *(const bf16x8*)(W0x + bo1[q]);
            acc[q] = __builtin_amdgcn_mfma_f32_16x16x32_bf16(ax, bx, acc[q], 0, 0, 0);
        }
        {
            bf16x8 af[8];
            const char* base = hA + p * 8448 + aoff;
            #pragma unroll
            for (int kt = 0; kt < 8; kt++) af[kt] = *(const bf16x8*)(base + kt * 64);
            #pragma unroll
            for (int kt = 0; kt < 8; kt++) {
                #pragma unroll
                for (int q = 0; q < 8; q++) {
                    bf16x8 bw = *(const bf16x8*)(W0h + bo8[q] + kt * 1024);
                    acc[q] = __builtin_amdgcn_mfma_f32_16x16x32_bf16(af[kt], bw, acc[q], 0, 0, 0);
                }
            }
        }
        // EW-A: c0,h0 update; write h0_new to ping-pong buffer
        #pragma unroll
        for (int h = 0; h < 2; h++) {
            #pragma unroll
            for (int r = 0; r < 4; r++) {
                float iv = acc[0 + h][r], fv = acc[2 + h][r], gv = acc[4 + h][r], ov = acc[6 + h][r];
                float cn = sigf(fv) * c0r[h][r] + sigf(iv) * tanhfast(gv);
                float hn = sigf(ov) * tanhfast(cn);
                c0r[h][r] = cn;
                h0b[p ^ 1][lq * 4 + r][wv * 32 + h * 16 + l15] = __float2bfloat16(hn);
            }
        }
        __syncthreads();

        // ---------- phase B: gates1 = h0_new @ w_ih1.T + h1 @ w_hh1.T + bias1 ----------
        #pragma unroll
        for (int q = 0; q < 8; q++) { f32x4 v = {bs1[q], bs1[q], bs1[q], bs1[q]}; acc[q] = v; }
        {
            bf16x8 a1[8], a2[8];
            const char* base1 = hA + (p ^ 1) * 8448 + aoff;
            const char* base2 = hB + p * 8448 + aoff;
            #pragma unroll
            for (int kt = 0; kt < 8; kt++) {
                a1[kt] = *(const bf16x8*)(base1 + kt * 64);
                a2[kt] = *(const bf16x8*)(base2 + kt * 64);
            }
            #pragma unroll
            for (int kt = 0; kt < 8; kt++) {
                #pragma unroll
                for (int q = 0; q < 8; q++) {
                    bf16x8 bw = *(const bf16x8*)(W1x + bo8[q] + kt * 1024);
                    acc[q] = __builtin_amdgcn_mfma_f32_16x16x32_bf16(a1[kt], bw, acc[q], 0, 0, 0);
                }
            }
            #pragma unroll
            for (int kt = 0; kt < 8; kt++) {
                #pragma unroll
                for (int q = 0; q < 8; q++) {
                    bf16x8 bw = *(const bf16x8*)(W1h + bo8[q] + kt * 1024);
                    acc[q] = __builtin_amdgcn_mfma_f32_16x16x32_bf16(a2[kt], bw, acc[q], 0, 0, 0);
                }
            }
        }
        // EW-B
        #pragma unroll
        for (int h = 0; h < 2; h++) {
            #pragma unroll
            for (int r = 0; r < 4; r++) {
                float iv = acc[0 + h][r], fv = acc[2 + h][r], gv = acc[4 + h][r], ov = acc[6 + h][r];
                float cn = sigf(fv) * c1r[h][r] + sigf(iv) * tanhfast(gv);
                float hn = sigf(ov) * tanhfast(cn);
                c1r[h][r] = cn;
                h1b[p ^ 1][lq * 4 + r][wv * 32 + h * 16 + l15] = __float2bfloat16(hn);
            }
        }
        __syncthreads();

        // ---------- phase C (wave 7 only): y = h1_new @ w_proj.T + b_proj -> out, x_{t+1} ----------
        if (wv == 7) {
            f32x4 py0 = {bpj0, bpj0, bpj0, bpj0};
            f32x4 py1 = {bpj1, bpj1, bpj1, bpj1};
            const char* baseh = hB + (p ^ 1) * 8448 + aoff;
            #pragma unroll
            for (int kt = 0; kt < 8; kt++) {
                bf16x8 ah  = *(const bf16x8*)(baseh + kt * 64);
                bf16x8 bf0 = *(const bf16x8*)(Wp + kt * 1024 + ln * 16);
                bf16x8 bf1 = *(const bf16x8*)(Wp + 8192 + kt * 1024 + ln * 16);
                py0 = __builtin_amdgcn_mfma_f32_16x16x32_bf16(ah, bf0, py0, 0, 0, 0);
                py1 = __builtin_amdgcn_mfma_f32_16x16x32_bf16(ah, bf1, py1, 0, 0, 0);
            }
            #pragma unroll
            for (int r = 0; r < 4; r++) {
                int b = lq * 4 + r;
                float y0 = py0[r];
                outp[(size_t)(b * TT + t) * DD + l15] = y0;
                xb[b][l15] = __float2bfloat16(y0);
                if (l15 < 4) {
                    float y1 = py1[r];
                    outp[(size_t)(b * TT + t) * DD + 16 + l15] = y1;
                    xb[b][16 + l15] = __float2bfloat16(y1);
                }
            }
        }
        __syncthreads();
    }
}

extern "C" void kernel_launch(void* const* d_in, const int* in_sizes, int n_in,
                              void* d_out, int out_size, void* d_ws, size_t ws_size,
                              hipStream_t stream) {
    const float* z      = (const float*)d_in[0];
    const float* w_lh   = (const float*)d_in[3];
    const float* b_lh   = (const float*)d_in[4];
    const float* w_lc   = (const float*)d_in[5];
    const float* b_lc   = (const float*)d_in[6];
    const float* w_ih0  = (const float*)d_in[7];
    const float* w_hh0  = (const float*)d_in[8];
    const float* b_ih0  = (const float*)d_in[9];
    const float* b_hh0  = (const float*)d_in[10];
    const float* w_ih1  = (const float*)d_in[11];
    const float* w_hh1  = (const float*)d_in[12];
    const float* b_ih1  = (const float*)d_in[13];
    const float* b_hh1  = (const float*)d_in[14];
    const float* w_proj = (const float*)d_in[15];
    const float* b_proj = (const float*)d_in[16];
    char* ws = (char*)d_ws;
    float* out = (float*)d_out;

    prep_kernel<<<3240, 256, 0, stream>>>(w_ih0, w_hh0, w_ih1, w_hh1, w_proj,
                                          b_ih0, b_hh0, b_ih1, b_hh1, ws);
    decoder_kernel<<<NBLK, 512, 0, stream>>>(z, w_lh, b_lh, w_lc, b_lc, b_proj, ws, out);
}